// Round 1
// baseline (4233.873 us; speedup 1.0000x reference)
//
#include <hip/hip_runtime.h>

#define T_DIM 512
#define B_DIM 256
#define I_DIM 64
#define H_DIM 128
#define P_DIM 256
#define O_DIM 50

typedef _Float16 half8 __attribute__((ext_vector_type(8)));
typedef float f32x4 __attribute__((ext_vector_type(4)));

#define GLOAD_LDS16(G, L)                                                      \
  __builtin_amdgcn_global_load_lds(                                            \
      (const __attribute__((address_space(1))) void*)(G),                      \
      (__attribute__((address_space(3))) void*)(L), 16, 0, 0)

__device__ __forceinline__ float sigm(float x) { return 1.f / (1.f + __expf(-x)); }
__device__ __forceinline__ float tanh_f(float x) {
  x = fminf(20.f, fmaxf(-20.f, x));
  float e = __expf(2.f * x);
  return (e - 1.f) / (e + 1.f);
}

// ---------------- elementwise fp32 -> fp16 ----------------
__global__ void cvt_k(const float* __restrict__ s, _Float16* __restrict__ d, long n) {
  long i = (long)blockIdx.x * blockDim.x + threadIdx.x;
  long st = (long)gridDim.x * blockDim.x;
  for (; i < n; i += st) d[i] = (_Float16)s[i];
}

// ---------------- mean over t of x -> xmean [B,I] ----------------
__global__ void xmean_k(const float* __restrict__ x, float* __restrict__ xm) {
  int b = blockIdx.x, i = threadIdx.x;  // 64 threads
  float s = 0.f;
  for (int t = 0; t < T_DIM; ++t) s += x[((long)t * B_DIM + b) * I_DIM + i];
  xm[b * I_DIM + i] = s * (1.0f / T_DIM);
}

// ---------------- skip_mean = xmean @ Ws^T + bs ----------------
__global__ void skip_k(const float* __restrict__ xm, const float* __restrict__ Wsk,
                       const float* __restrict__ bsk, float* __restrict__ skipm) {
  int b = blockIdx.x, p = threadIdx.x;  // 256 threads
  float s = bsk[p];
  for (int i = 0; i < I_DIM; ++i) s += xm[b * I_DIM + i] * Wsk[p * I_DIM + i];
  skipm[b * P_DIM + p] = s;
}

__global__ void zero2_k(float* a, float* b2) {
  int p = threadIdx.x;
  a[p] = 0.f;
  b2[p] = 0.f;
}

// ---------------- BN stats over proj (fp16) ----------------
__global__ void stats_k(const _Float16* __restrict__ proj, float* __restrict__ gsum,
                        float* __restrict__ gss) {
  int p = threadIdx.x;
  long r0 = (long)blockIdx.x * 256;
  float s = 0.f, ss = 0.f;
  for (int r = 0; r < 256; ++r) {
    float v = (float)proj[(r0 + r) * P_DIM + p];
    s += v;
    ss += v * v;
  }
  atomicAdd(&gsum[p], s);
  atomicAdd(&gss[p], ss);
}

__global__ void bnprep_k(const float* gsum, const float* gss, const float* gamma,
                         const float* beta, float* bns, float* bnt) {
  int p = threadIdx.x;
  const float inv = 1.0f / ((float)T_DIM * (float)B_DIM);
  float m = gsum[p] * inv;
  float v = gss[p] * inv - m * m;
  float rs = rsqrtf(v + 1e-5f);
  float s = gamma[p] * rs;
  bns[p] = s;
  bnt[p] = beta[p] - m * s;
}

// fold BN affine into Wcih (per-column scale) + bias
__global__ void fold_k(const float* __restrict__ Wcih, const float* __restrict__ bcih,
                       const float* __restrict__ bns, const float* __restrict__ bnt,
                       _Float16* __restrict__ WF, float* __restrict__ bF) {
  __shared__ float red[256];
  int n = blockIdx.x, k = threadIdx.x;
  float wv = Wcih[n * 256 + k];
  WF[n * 256 + k] = (_Float16)(wv * bns[k]);
  red[k] = wv * bnt[k];
  __syncthreads();
  for (int s = 128; s > 0; s >>= 1) {
    if (k < s) red[k] += red[k + s];
    __syncthreads();
  }
  if (k == 0) bF[n] = bcih[n] + red[0];
}

// ---------------- fp16 MFMA GEMM: C[M,N] = A[M,K] @ W[N,K]^T + bias (+bias2 for n<n2lim) ----
__global__ __launch_bounds__(256) void gemm_k(
    const _Float16* __restrict__ A, const _Float16* __restrict__ W,
    const float* __restrict__ bias, const float* __restrict__ bias2, int n2lim,
    _Float16* __restrict__ C, int M, int N, int K) {
  __shared__ __align__(16) _Float16 As[128 * 64];
  __shared__ __align__(16) _Float16 Bs[128 * 64];
  const int tid = threadIdx.x;
  const int l = tid & 63;
  const int w = tid >> 6;
  const int wr = w >> 1, wc = w & 1;
  const int lrow = l & 15, lk = l >> 4;
  const long bm = blockIdx.x, bn = blockIdx.y;

  f32x4 z = {0.f, 0.f, 0.f, 0.f};
  f32x4 acc[4][4];
#pragma unroll
  for (int m = 0; m < 4; ++m)
#pragma unroll
    for (int n = 0; n < 4; ++n) acc[m][n] = z;

  for (int k0 = 0; k0 < K; k0 += 64) {
    if (k0) __syncthreads();
#pragma unroll
    for (int it = 0; it < 4; ++it) {
      const int lin = it * 256 + tid;
      const int row = lin >> 3, slot = lin & 7;
      const int scol = (slot ^ (row & 7)) << 3;  // pre-swizzled global source
      GLOAD_LDS16(A + (bm * 128 + row) * (long)K + k0 + scol, (_Float16*)As + (size_t)lin * 8);
      GLOAD_LDS16(W + (bn * 128 + row) * (long)K + k0 + scol, (_Float16*)Bs + (size_t)lin * 8);
    }
    __syncthreads();
#pragma unroll
    for (int kk = 0; kk < 2; ++kk) {
      half8 af[4], wfr[4];
#pragma unroll
      for (int m = 0; m < 4; ++m) {
        const int row = wr * 64 + m * 16 + lrow;
        af[m] = *(const half8*)((const char*)As +
                                ((row * 128 + (kk * 32 + lk * 8) * 2) ^ ((row & 7) << 4)));
      }
#pragma unroll
      for (int n = 0; n < 4; ++n) {
        const int row = wc * 64 + n * 16 + lrow;
        wfr[n] = *(const half8*)((const char*)Bs +
                                 ((row * 128 + (kk * 32 + lk * 8) * 2) ^ ((row & 7) << 4)));
      }
#pragma unroll
      for (int m = 0; m < 4; ++m)
#pragma unroll
        for (int n = 0; n < 4; ++n)
          acc[m][n] = __builtin_amdgcn_mfma_f32_16x16x32_f16(af[m], wfr[n], acc[m][n], 0, 0, 0);
    }
  }
#pragma unroll
  for (int n = 0; n < 4; ++n) {
    const int gn = (int)bn * 128 + wc * 64 + n * 16 + lrow;
    float bv = 0.f;
    if (bias) bv += bias[gn];
    if (bias2 && gn < n2lim) bv += bias2[gn];
#pragma unroll
    for (int m = 0; m < 4; ++m)
#pragma unroll
      for (int r = 0; r < 4; ++r) {
        const long gm = bm * 128 + wr * 64 + m * 16 + lk * 4 + r;
        C[gm * (long)N + gn] = (_Float16)(acc[m][n][r] + bv);
      }
  }
}

// ---------------- GRU layer scan: 16 blocks x 16 rows, weights in registers ----------------
__global__ __launch_bounds__(256) void scan_layer(
    const _Float16* __restrict__ xp,  // [TC*B, 384] incl. bih + bhh(r,z)
    _Float16* __restrict__ y,         // [TC*B, 128] out (chunk-offset applied by host)
    float* __restrict__ hst, const float* __restrict__ h0init,
    const _Float16* __restrict__ Whh, const float* __restrict__ bhh, int TC, int first) {
  __shared__ __align__(16) _Float16 hL[2][16 * 128];
  const int tid = threadIdx.x;
  const int l = tid & 63, w = tid >> 6;  // 4 waves
  const int lrow = l & 15, lk = l >> 4;
  const int rbase = blockIdx.x * 16;

  half8 wf[6][4];  // [gate*2+c][kk] B-fragments, resident
#pragma unroll
  for (int g = 0; g < 3; ++g)
#pragma unroll
    for (int c = 0; c < 2; ++c) {
      const int nt = g * 8 + 2 * w + c;
#pragma unroll
      for (int kk = 0; kk < 4; ++kk)
        wf[g * 2 + c][kk] =
            *(const half8*)(Whh + (size_t)(nt * 16 + lrow) * H_DIM + kk * 32 + lk * 8);
    }
  float bN[2];
#pragma unroll
  for (int c = 0; c < 2; ++c) bN[c] = bhh[2 * H_DIM + 32 * w + 16 * c + lrow];

  const float* hsrc = first ? h0init : hst;
  float h[2][4];
#pragma unroll
  for (int c = 0; c < 2; ++c)
#pragma unroll
    for (int r = 0; r < 4; ++r)
      h[c][r] = hsrc[(rbase + lk * 4 + r) * H_DIM + 32 * w + 16 * c + lrow];
  for (int i = tid; i < 16 * 128; i += 256) {
    int row = i >> 7, p = i & 127;
    int byte = (row * 256 + p * 2) ^ ((row & 7) << 4);
    *(_Float16*)((char*)hL[0] + byte) = (_Float16)hsrc[(rbase + row) * H_DIM + p];
  }
  __syncthreads();

  _Float16 xA[3][2][4], xB[3][2][4];
  auto loadx = [&](_Float16(&X)[3][2][4], int tt) {
#pragma unroll
    for (int g = 0; g < 3; ++g)
#pragma unroll
      for (int c = 0; c < 2; ++c)
#pragma unroll
        for (int r = 0; r < 4; ++r)
          X[g][c][r] = xp[((long)tt * B_DIM + rbase + lk * 4 + r) * (3 * H_DIM) + g * H_DIM +
                          32 * w + 16 * c + lrow];
  };
  auto step = [&](int tt, _Float16(&XC)[3][2][4], _Float16(&XN)[3][2][4], int tn) {
    loadx(XN, tn);  // prefetch next step's xp
    char* hCur = (char*)hL[tt & 1];
    char* hNxt = (char*)hL[(tt & 1) ^ 1];
    half8 af[4];
#pragma unroll
    for (int kk = 0; kk < 4; ++kk) {
      int byte = (lrow * 256 + (kk * 32 + lk * 8) * 2) ^ ((lrow & 7) << 4);
      af[kk] = *(const half8*)(hCur + byte);
    }
    f32x4 acc[3][2];
#pragma unroll
    for (int g = 0; g < 3; ++g)
#pragma unroll
      for (int c = 0; c < 2; ++c) {
        f32x4 a = {0.f, 0.f, 0.f, 0.f};
#pragma unroll
        for (int kk = 0; kk < 4; ++kk)
          a = __builtin_amdgcn_mfma_f32_16x16x32_f16(af[kk], wf[g * 2 + c][kk], a, 0, 0, 0);
        acc[g][c] = a;
      }
#pragma unroll
    for (int c = 0; c < 2; ++c)
#pragma unroll
      for (int r = 0; r < 4; ++r) {
        float rg = sigm((float)XC[0][c][r] + acc[0][c][r]);
        float zg = sigm((float)XC[1][c][r] + acc[1][c][r]);
        float ng = tanh_f((float)XC[2][c][r] + rg * (acc[2][c][r] + bN[c]));
        float hv = (1.f - zg) * ng + zg * h[c][r];
        h[c][r] = hv;
        const int row = lk * 4 + r, p = 32 * w + 16 * c + lrow;
        y[((long)tt * B_DIM + rbase + row) * H_DIM + p] = (_Float16)hv;
        int byte = (row * 256 + p * 2) ^ ((row & 7) << 4);
        *(_Float16*)(hNxt + byte) = (_Float16)hv;
      }
    __syncthreads();
  };
  loadx(xA, 0);
  for (int t = 0; t < TC; t += 2) {
    step(t, xA, xB, t + 1);
    step(t + 1, xB, xA, (t + 2 < TC) ? t + 2 : TC - 1);
  }
#pragma unroll
  for (int c = 0; c < 2; ++c)
#pragma unroll
    for (int r = 0; r < 4; ++r)
      hst[(rbase + lk * 4 + r) * H_DIM + 32 * w + 16 * c + lrow] = h[c][r];
}

// ---------------- GRUCell scan (P=256): 16 blocks x 8 waves ----------------
__global__ __launch_bounds__(512) void scan_cell(
    const _Float16* __restrict__ xp,  // [TC*B, 768] incl. folded biases
    float* __restrict__ hst, float* __restrict__ agg, const _Float16* __restrict__ Whh,
    const float* __restrict__ bhh, int TC, int first) {
  __shared__ __align__(16) _Float16 hL[2][16 * 256];
  __shared__ __align__(16) _Float16 WL[768 * 64];  // K-slice [192,256) of Wchh, swizzled
  const int tid = threadIdx.x;
  const int l = tid & 63, w = tid >> 6;  // 8 waves
  const int lrow = l & 15, lk = l >> 4;
  const int rbase = blockIdx.x * 16;

  half8 wf[6][6];  // kk 0..5 resident (144 VGPR); kk 6..7 from LDS
#pragma unroll
  for (int g = 0; g < 3; ++g)
#pragma unroll
    for (int c = 0; c < 2; ++c) {
      const int nt = g * 16 + 2 * w + c;
#pragma unroll
      for (int kk = 0; kk < 6; ++kk)
        wf[g * 2 + c][kk] =
            *(const half8*)(Whh + (size_t)(nt * 16 + lrow) * P_DIM + kk * 32 + lk * 8);
    }
  for (int q = tid; q < 768 * 8; q += 512) {
    int row = q >> 3, slot = q & 7;
    int scol = (slot ^ (row & 7)) << 3;
    *(half8*)((char*)WL + (size_t)q * 16) = *(const half8*)(Whh + (size_t)row * P_DIM + 192 + scol);
  }
  float bN[2];
#pragma unroll
  for (int c = 0; c < 2; ++c) bN[c] = bhh[2 * P_DIM + 32 * w + 16 * c + lrow];

  float h[2][4], ag[2][4];
#pragma unroll
  for (int c = 0; c < 2; ++c)
#pragma unroll
    for (int r = 0; r < 4; ++r) {
      h[c][r] = first ? 0.f : hst[(rbase + lk * 4 + r) * P_DIM + 32 * w + 16 * c + lrow];
      ag[c][r] = 0.f;
    }
  for (int i = tid; i < 16 * 256; i += 512) {
    int row = i >> 8, p = i & 255;
    float hv = first ? 0.f : hst[(rbase + row) * P_DIM + p];
    int byte = (row * 512 + p * 2) ^ ((row & 7) << 4);
    *(_Float16*)((char*)hL[0] + byte) = (_Float16)hv;
  }
  __syncthreads();

  _Float16 xC[3][2][4];
  auto loadx = [&](int tt) {
#pragma unroll
    for (int g = 0; g < 3; ++g)
#pragma unroll
      for (int c = 0; c < 2; ++c)
#pragma unroll
        for (int r = 0; r < 4; ++r)
          xC[g][c][r] = xp[((long)tt * B_DIM + rbase + lk * 4 + r) * (3 * P_DIM) + g * P_DIM +
                           32 * w + 16 * c + lrow];
  };
  auto step = [&](int tt, int tn) {
    char* hCur = (char*)hL[tt & 1];
    char* hNxt = (char*)hL[(tt & 1) ^ 1];
    half8 af[4];
    f32x4 acc[3][2];
#pragma unroll
    for (int kk = 0; kk < 4; ++kk) {
      int byte = (lrow * 512 + (kk * 32 + lk * 8) * 2) ^ ((lrow & 7) << 4);
      af[kk] = *(const half8*)(hCur + byte);
    }
#pragma unroll
    for (int g = 0; g < 3; ++g)
#pragma unroll
      for (int c = 0; c < 2; ++c) {
        f32x4 a = {0.f, 0.f, 0.f, 0.f};
#pragma unroll
        for (int kk = 0; kk < 4; ++kk)
          a = __builtin_amdgcn_mfma_f32_16x16x32_f16(af[kk], wf[g * 2 + c][kk], a, 0, 0, 0);
        acc[g][c] = a;
      }
#pragma unroll
    for (int kk = 0; kk < 4; ++kk) {
      int byte = (lrow * 512 + ((kk + 4) * 32 + lk * 8) * 2) ^ ((lrow & 7) << 4);
      af[kk] = *(const half8*)(hCur + byte);
    }
#pragma unroll
    for (int g = 0; g < 3; ++g)
#pragma unroll
      for (int c = 0; c < 2; ++c) {
        const int nt = g * 16 + 2 * w + c;
        const int wrow = nt * 16 + lrow;
        f32x4 a = acc[g][c];
        a = __builtin_amdgcn_mfma_f32_16x16x32_f16(af[0], wf[g * 2 + c][4], a, 0, 0, 0);
        a = __builtin_amdgcn_mfma_f32_16x16x32_f16(af[1], wf[g * 2 + c][5], a, 0, 0, 0);
        half8 w6 = *(const half8*)((char*)WL + ((wrow * 128 + lk * 16) ^ ((wrow & 7) << 4)));
        half8 w7 = *(const half8*)((char*)WL + ((wrow * 128 + 64 + lk * 16) ^ ((wrow & 7) << 4)));
        a = __builtin_amdgcn_mfma_f32_16x16x32_f16(af[2], w6, a, 0, 0, 0);
        a = __builtin_amdgcn_mfma_f32_16x16x32_f16(af[3], w7, a, 0, 0, 0);
        acc[g][c] = a;
      }
#pragma unroll
    for (int c = 0; c < 2; ++c)
#pragma unroll
      for (int r = 0; r < 4; ++r) {
        float rg = sigm((float)xC[0][c][r] + acc[0][c][r]);
        float zg = sigm((float)xC[1][c][r] + acc[1][c][r]);
        float ng = tanh_f((float)xC[2][c][r] + rg * (acc[2][c][r] + bN[c]));
        float hv = (1.f - zg) * ng + zg * h[c][r];
        h[c][r] = hv;
        ag[c][r] += 0.5f * hv * (1.f + erff(hv * 0.70710678118f));
        const int row = lk * 4 + r, p = 32 * w + 16 * c + lrow;
        int byte = (row * 512 + p * 2) ^ ((row & 7) << 4);
        *(_Float16*)(hNxt + byte) = (_Float16)hv;
      }
    loadx(tn);
    __syncthreads();
  };
  loadx(0);
  for (int t = 0; t < TC; t += 2) {
    step(t, t + 1);
    step(t + 1, (t + 2 < TC) ? t + 2 : TC - 1);
  }
#pragma unroll
  for (int c = 0; c < 2; ++c)
#pragma unroll
    for (int r = 0; r < 4; ++r) {
      const int gi = (rbase + lk * 4 + r) * P_DIM + 32 * w + 16 * c + lrow;
      hst[gi] = h[c][r];
      float prev = first ? 0.f : agg[gi];
      agg[gi] = prev + ag[c][r];
    }
}

// ---------------- final: out = (agg/T + skipm) @ Wf^T + bf ----------------
__global__ void final_k(const float* __restrict__ agg, const float* __restrict__ skipm,
                        const float* __restrict__ Wf, const float* __restrict__ bfb,
                        float* __restrict__ out) {
  int b = blockIdx.x, o = threadIdx.x;  // 64 threads
  if (o >= O_DIM) return;
  float s = bfb[o];
  for (int p = 0; p < P_DIM; ++p)
    s += (agg[b * P_DIM + p] * (1.0f / T_DIM) + skipm[b * P_DIM + p]) * Wf[o * P_DIM + p];
  out[b * O_DIM + o] = s;
}

extern "C" void kernel_launch(void* const* d_in, const int* in_sizes, int n_in, void* d_out,
                              int out_size, void* d_ws, size_t ws_size, hipStream_t stream) {
  const float* x = (const float*)d_in[0];
  const float* h0 = (const float*)d_in[1];
  const float* Wih0 = (const float*)d_in[2];
  const float* Whh0f = (const float*)d_in[3];
  const float* bih0 = (const float*)d_in[4];
  const float* bhh0 = (const float*)d_in[5];
  const float* Wih1 = (const float*)d_in[6];
  const float* Whh1f = (const float*)d_in[7];
  const float* bih1 = (const float*)d_in[8];
  const float* bhh1 = (const float*)d_in[9];
  const float* Wp = (const float*)d_in[10];
  const float* bp = (const float*)d_in[11];
  const float* gamma = (const float*)d_in[12];
  const float* beta = (const float*)d_in[13];
  const float* Wcih = (const float*)d_in[14];
  const float* Wchhf = (const float*)d_in[15];
  const float* bcih = (const float*)d_in[16];
  const float* bchh = (const float*)d_in[17];
  const float* Wsk = (const float*)d_in[18];
  const float* bsk = (const float*)d_in[19];
  const float* Wf = (const float*)d_in[20];
  const float* bfb = (const float*)d_in[21];
  float* out = (float*)d_out;

  char* wsp = (char*)d_ws;
  size_t off = 0;
  auto alloc = [&](size_t b) -> void* {
    void* p = wsp + off;
    off = (off + b + 255) & ~(size_t)255;
    return p;
  };
  _Float16* xh = (_Float16*)alloc((size_t)T_DIM * B_DIM * I_DIM * 2);
  _Float16* wih0 = (_Float16*)alloc(384 * 64 * 2);
  _Float16* whh0 = (_Float16*)alloc(384 * 128 * 2);
  _Float16* wih1 = (_Float16*)alloc(384 * 128 * 2);
  _Float16* whh1 = (_Float16*)alloc(384 * 128 * 2);
  _Float16* wp = (_Float16*)alloc(256 * 128 * 2);
  _Float16* wcihF = (_Float16*)alloc(768 * 256 * 2);
  _Float16* wchh = (_Float16*)alloc(768 * 256 * 2);
  _Float16* y01 = (_Float16*)alloc((size_t)T_DIM * B_DIM * H_DIM * 2);
  _Float16* proj = (_Float16*)alloc((size_t)T_DIM * B_DIM * P_DIM * 2);
  float* hst0 = (float*)alloc(B_DIM * H_DIM * 4);
  float* hst1 = (float*)alloc(B_DIM * H_DIM * 4);
  float* hstc = (float*)alloc(B_DIM * P_DIM * 4);
  float* agg = (float*)alloc(B_DIM * P_DIM * 4);
  float* xm = (float*)alloc(B_DIM * I_DIM * 4);
  float* skipm = (float*)alloc(B_DIM * P_DIM * 4);
  float* gsum = (float*)alloc(256 * 4);
  float* gss = (float*)alloc(256 * 4);
  float* bns = (float*)alloc(256 * 4);
  float* bnt = (float*)alloc(256 * 4);
  float* bcihF = (float*)alloc(768 * 4);

  int TC = 512;  // time-chunk; shrink until xp chunk buffer fits in ws
  while (TC > 8 && off + (size_t)TC * B_DIM * 768 * 2 > ws_size) TC >>= 1;
  _Float16* xpb = (_Float16*)alloc((size_t)TC * B_DIM * 768 * 2);
  const int nc = T_DIM / TC;
  const int M = TC * B_DIM;

  auto cvt = [&](const float* s, _Float16* d, long n) {
    long g = (n + 255) / 256;
    if (g > 2048) g = 2048;
    cvt_k<<<dim3((unsigned)g), dim3(256), 0, stream>>>(s, d, n);
  };
  cvt(x, xh, (long)T_DIM * B_DIM * I_DIM);
  cvt(Wih0, wih0, 384 * 64);
  cvt(Whh0f, whh0, 384 * 128);
  cvt(Wih1, wih1, 384 * 128);
  cvt(Whh1f, whh1, 384 * 128);
  cvt(Wp, wp, 256 * 128);
  cvt(Wchhf, wchh, 768 * 256);

  xmean_k<<<B_DIM, I_DIM, 0, stream>>>(x, xm);
  skip_k<<<B_DIM, P_DIM, 0, stream>>>(xm, Wsk, bsk, skipm);
  zero2_k<<<1, 256, 0, stream>>>(gsum, gss);

  for (int c = 0; c < nc; ++c) {
    const _Float16* xc = xh + (size_t)c * TC * B_DIM * I_DIM;
    _Float16* yc = y01 + (size_t)c * TC * B_DIM * H_DIM;
    _Float16* pc = proj + (size_t)c * TC * B_DIM * P_DIM;
    gemm_k<<<dim3(M / 128, 3), 256, 0, stream>>>(xc, wih0, bih0, bhh0, 2 * H_DIM, xpb, M,
                                                 3 * H_DIM, I_DIM);
    scan_layer<<<16, 256, 0, stream>>>(xpb, yc, hst0, h0, whh0, bhh0, TC, c == 0);
    gemm_k<<<dim3(M / 128, 3), 256, 0, stream>>>(yc, wih1, bih1, bhh1, 2 * H_DIM, xpb, M,
                                                 3 * H_DIM, H_DIM);
    scan_layer<<<16, 256, 0, stream>>>(xpb, yc, hst1, h0 + B_DIM * H_DIM, whh1, bhh1, TC, c == 0);
    gemm_k<<<dim3(M / 128, 2), 256, 0, stream>>>(yc, wp, bp, (const float*)nullptr, 0, pc, M,
                                                 P_DIM, H_DIM);
  }
  stats_k<<<512, 256, 0, stream>>>(proj, gsum, gss);
  bnprep_k<<<1, 256, 0, stream>>>(gsum, gss, gamma, beta, bns, bnt);
  fold_k<<<768, 256, 0, stream>>>(Wcih, bcih, bns, bnt, wcihF, bcihF);
  for (int c = 0; c < nc; ++c) {
    const _Float16* pc = proj + (size_t)c * TC * B_DIM * P_DIM;
    gemm_k<<<dim3(M / 128, 6), 256, 0, stream>>>(pc, wcihF, bcihF, bchh, 2 * P_DIM, xpb, M,
                                                 3 * P_DIM, P_DIM);
    scan_cell<<<16, 512, 0, stream>>>(xpb, hstc, agg, wchh, bchh, TC, c == 0);
  }
  final_k<<<B_DIM, 64, 0, stream>>>(agg, skipm, Wf, bfb, out);
}

// Round 2
// 3618.056 us; speedup vs baseline: 1.1702x; 1.1702x over previous
//
#include <hip/hip_runtime.h>

#define T_DIM 512
#define B_DIM 256
#define I_DIM 64
#define H_DIM 128
#define P_DIM 256
#define O_DIM 50

typedef _Float16 half8 __attribute__((ext_vector_type(8)));
typedef _Float16 half4 __attribute__((ext_vector_type(4)));
typedef float f32x4 __attribute__((ext_vector_type(4)));

#define GLOAD_LDS16(G, L)                                                      \
  __builtin_amdgcn_global_load_lds(                                            \
      (const __attribute__((address_space(1))) void*)(G),                      \
      (__attribute__((address_space(3))) void*)(L), 16, 0, 0)

__device__ __forceinline__ float sigm(float x) { return 1.f / (1.f + __expf(-x)); }
__device__ __forceinline__ float tanh_f(float x) {
  x = fminf(20.f, fmaxf(-20.f, x));
  float e = __expf(2.f * x);
  return (e - 1.f) / (e + 1.f);
}

// ---------------- elementwise fp32 -> fp16 ----------------
__global__ void cvt_k(const float* __restrict__ s, _Float16* __restrict__ d, long n) {
  long i = (long)blockIdx.x * blockDim.x + threadIdx.x;
  long st = (long)gridDim.x * blockDim.x;
  for (; i < n; i += st) d[i] = (_Float16)s[i];
}

// ---------------- mean over t of x -> xmean [B,I] ----------------
__global__ void xmean_k(const float* __restrict__ x, float* __restrict__ xm) {
  int b = blockIdx.x, i = threadIdx.x;  // 64 threads
  float s = 0.f;
  for (int t = 0; t < T_DIM; ++t) s += x[((long)t * B_DIM + b) * I_DIM + i];
  xm[b * I_DIM + i] = s * (1.0f / T_DIM);
}

// ---------------- skip_mean = xmean @ Ws^T + bs ----------------
__global__ void skip_k(const float* __restrict__ xm, const float* __restrict__ Wsk,
                       const float* __restrict__ bsk, float* __restrict__ skipm) {
  int b = blockIdx.x, p = threadIdx.x;  // 256 threads
  float s = bsk[p];
  for (int i = 0; i < I_DIM; ++i) s += xm[b * I_DIM + i] * Wsk[p * I_DIM + i];
  skipm[b * P_DIM + p] = s;
}

__global__ void zero2_k(float* a, float* b2) {
  int p = threadIdx.x;
  a[p] = 0.f;
  b2[p] = 0.f;
}

// ---------------- BN stats over proj (fp16, row-major) ----------------
__global__ void stats_k(const _Float16* __restrict__ proj, float* __restrict__ gsum,
                        float* __restrict__ gss) {
  int p = threadIdx.x;
  long r0 = (long)blockIdx.x * 256;
  float s = 0.f, ss = 0.f;
  for (int r = 0; r < 256; ++r) {
    float v = (float)proj[(r0 + r) * P_DIM + p];
    s += v;
    ss += v * v;
  }
  atomicAdd(&gsum[p], s);
  atomicAdd(&gss[p], ss);
}

__global__ void bnprep_k(const float* gsum, const float* gss, const float* gamma,
                         const float* beta, float* bns, float* bnt) {
  int p = threadIdx.x;
  const float inv = 1.0f / ((float)T_DIM * (float)B_DIM);
  float m = gsum[p] * inv;
  float v = gss[p] * inv - m * m;
  float rs = rsqrtf(v + 1e-5f);
  float s = gamma[p] * rs;
  bns[p] = s;
  bnt[p] = beta[p] - m * s;
}

// fold BN affine into Wcih (per-column scale) + bias
__global__ void fold_k(const float* __restrict__ Wcih, const float* __restrict__ bcih,
                       const float* __restrict__ bns, const float* __restrict__ bnt,
                       _Float16* __restrict__ WF, float* __restrict__ bF) {
  __shared__ float red[256];
  int n = blockIdx.x, k = threadIdx.x;
  float wv = Wcih[n * 256 + k];
  WF[n * 256 + k] = (_Float16)(wv * bns[k]);
  red[k] = wv * bnt[k];
  __syncthreads();
  for (int s = 128; s > 0; s >>= 1) {
    if (k < s) red[k] += red[k + s];
    __syncthreads();
  }
  if (k == 0) bF[n] = bcih[n] + red[0];
}

// ---------------- fp16 MFMA GEMM: C = A[M,K] @ W[N,K]^T + bias (+bias2 n<n2lim)
// transN=0: C row-major [M][N].  transN=1: C = [t][N][B] with M = t*256+b.
__global__ __launch_bounds__(256) void gemm_k(
    const _Float16* __restrict__ A, const _Float16* __restrict__ W,
    const float* __restrict__ bias, const float* __restrict__ bias2, int n2lim,
    _Float16* __restrict__ C, int M, int N, int K, int transN) {
  __shared__ __align__(16) _Float16 As[128 * 64];
  __shared__ __align__(16) _Float16 Bs[128 * 64];
  const int tid = threadIdx.x;
  const int l = tid & 63;
  const int w = tid >> 6;
  const int wr = w >> 1, wc = w & 1;
  const int lrow = l & 15, lk = l >> 4;
  const long bm = blockIdx.x, bn = blockIdx.y;

  f32x4 z = {0.f, 0.f, 0.f, 0.f};
  f32x4 acc[4][4];
#pragma unroll
  for (int m = 0; m < 4; ++m)
#pragma unroll
    for (int n = 0; n < 4; ++n) acc[m][n] = z;

  for (int k0 = 0; k0 < K; k0 += 64) {
    if (k0) __syncthreads();
#pragma unroll
    for (int it = 0; it < 4; ++it) {
      const int lin = it * 256 + tid;
      const int row = lin >> 3, slot = lin & 7;
      const int scol = (slot ^ (row & 7)) << 3;  // pre-swizzled global source
      GLOAD_LDS16(A + (bm * 128 + row) * (long)K + k0 + scol, (_Float16*)As + (size_t)lin * 8);
      GLOAD_LDS16(W + (bn * 128 + row) * (long)K + k0 + scol, (_Float16*)Bs + (size_t)lin * 8);
    }
    __syncthreads();
#pragma unroll
    for (int kk = 0; kk < 2; ++kk) {
      half8 af[4], wfr[4];
#pragma unroll
      for (int m = 0; m < 4; ++m) {
        const int row = wr * 64 + m * 16 + lrow;
        af[m] = *(const half8*)((const char*)As +
                                ((row * 128 + (kk * 32 + lk * 8) * 2) ^ ((row & 7) << 4)));
      }
#pragma unroll
      for (int n = 0; n < 4; ++n) {
        const int row = wc * 64 + n * 16 + lrow;
        wfr[n] = *(const half8*)((const char*)Bs +
                                 ((row * 128 + (kk * 32 + lk * 8) * 2) ^ ((row & 7) << 4)));
      }
#pragma unroll
      for (int m = 0; m < 4; ++m)
#pragma unroll
        for (int n = 0; n < 4; ++n)
          acc[m][n] = __builtin_amdgcn_mfma_f32_16x16x32_f16(af[m], wfr[n], acc[m][n], 0, 0, 0);
    }
  }
  if (transN) {
    const long tIdx = bm >> 1;  // B=256, 128-row tiles
    const int bbase = (int)(bm & 1) * 128 + wr * 64 + lk * 4;
#pragma unroll
    for (int n = 0; n < 4; ++n) {
      const int gn = (int)bn * 128 + wc * 64 + n * 16 + lrow;
      float bv = 0.f;
      if (bias) bv += bias[gn];
      if (bias2 && gn < n2lim) bv += bias2[gn];
#pragma unroll
      for (int m = 0; m < 4; ++m) {
        half4 v;
#pragma unroll
        for (int r = 0; r < 4; ++r) v[r] = (_Float16)(acc[m][n][r] + bv);
        *(half4*)(C + (tIdx * N + gn) * 256 + bbase + m * 16) = v;
      }
    }
  } else {
#pragma unroll
    for (int n = 0; n < 4; ++n) {
      const int gn = (int)bn * 128 + wc * 64 + n * 16 + lrow;
      float bv = 0.f;
      if (bias) bv += bias[gn];
      if (bias2 && gn < n2lim) bv += bias2[gn];
#pragma unroll
      for (int m = 0; m < 4; ++m)
#pragma unroll
        for (int r = 0; r < 4; ++r) {
          const long gm = bm * 128 + wr * 64 + m * 16 + lk * 4 + r;
          C[gm * (long)N + gn] = (_Float16)(acc[m][n][r] + bv);
        }
    }
  }
}

// ---------------- GRU layer scan: 16 blocks x 8 waves, 4 h/thread ----------------
__global__ __launch_bounds__(512) void scan_layer(
    const _Float16* __restrict__ xpT,  // [TC][384][B] incl. bih + bhh(r,z)
    _Float16* __restrict__ y,          // [TC*B][128] row-major
    float* __restrict__ hst, const float* __restrict__ h0init,
    const _Float16* __restrict__ Whh, const float* __restrict__ bhh, int TC, int first) {
  __shared__ __align__(16) _Float16 hL[2][16 * 128];
  const int tid = threadIdx.x;
  const int l = tid & 63, w = tid >> 6;  // 8 waves
  const int lrow = l & 15, lk = l >> 4;
  const int rbase = blockIdx.x * 16;
  const int p = w * 16 + lrow;

  half8 wf[3][4];  // wave owns p-tile w for all 3 gates
#pragma unroll
  for (int g = 0; g < 3; ++g)
#pragma unroll
    for (int kk = 0; kk < 4; ++kk)
      wf[g][kk] = *(const half8*)(Whh + (size_t)(g * 128 + p) * H_DIM + kk * 32 + lk * 8);
  const float bN = bhh[2 * H_DIM + p];

  const float* hsrc = first ? h0init : hst;
  float h[4];
#pragma unroll
  for (int r = 0; r < 4; ++r) h[r] = hsrc[(rbase + lk * 4 + r) * H_DIM + p];
  for (int i = tid; i < 16 * 128; i += 512) {
    int row = i >> 7, pp = i & 127;
    int byte = (row * 256 + pp * 2) ^ ((row & 7) << 4);
    *(_Float16*)((char*)hL[0] + byte) = (_Float16)hsrc[(rbase + row) * H_DIM + pp];
  }
  __syncthreads();

  half4 xA[3], xB[3];
  auto loadx = [&](half4(&X)[3], int tt) {
#pragma unroll
    for (int g = 0; g < 3; ++g)
      X[g] = *(const half4*)(xpT + ((long)tt * 384 + g * 128 + p) * 256 + rbase + lk * 4);
  };
  auto step = [&](int tt, half4(&XC)[3], half4(&XN)[3], int tn) {
    loadx(XN, tn);  // prefetch next step's xp
    char* hCur = (char*)hL[tt & 1];
    char* hNxt = (char*)hL[(tt & 1) ^ 1];
    half8 af[4];
#pragma unroll
    for (int kk = 0; kk < 4; ++kk) {
      int byte = (lrow * 256 + (kk * 32 + lk * 8) * 2) ^ ((lrow & 7) << 4);
      af[kk] = *(const half8*)(hCur + byte);
    }
    f32x4 acc[3];
#pragma unroll
    for (int r = 0; r < 4; ++r) {
      acc[0][r] = (float)XC[0][r];
      acc[1][r] = (float)XC[1][r];
      acc[2][r] = 0.f;
    }
#pragma unroll
    for (int g = 0; g < 3; ++g)
#pragma unroll
      for (int kk = 0; kk < 4; ++kk)
        acc[g] = __builtin_amdgcn_mfma_f32_16x16x32_f16(af[kk], wf[g][kk], acc[g], 0, 0, 0);
#pragma unroll
    for (int r = 0; r < 4; ++r) {
      float rg = sigm(acc[0][r]);
      float zg = sigm(acc[1][r]);
      float ng = tanh_f((float)XC[2][r] + rg * (acc[2][r] + bN));
      float hv = (1.f - zg) * ng + zg * h[r];
      h[r] = hv;
      const int row = lk * 4 + r;
      y[((long)tt * B_DIM + rbase + row) * H_DIM + p] = (_Float16)hv;
      int byte = (row * 256 + p * 2) ^ ((row & 7) << 4);
      *(_Float16*)(hNxt + byte) = (_Float16)hv;
    }
    __syncthreads();
  };
  loadx(xA, 0);
  for (int t = 0; t < TC; t += 2) {
    step(t, xA, xB, t + 1);
    step(t + 1, xB, xA, (t + 2 < TC) ? t + 2 : TC - 1);
  }
#pragma unroll
  for (int r = 0; r < 4; ++r) hst[(rbase + lk * 4 + r) * H_DIM + p] = h[r];
}

// ---------------- GRUCell scan (P=256): 16 blocks x 8 waves ----------------
__global__ __launch_bounds__(512) void scan_cell(
    const _Float16* __restrict__ xpT,  // [TC][768][B] incl. folded biases
    _Float16* __restrict__ hT,         // [TC][256][B] (chunk-offset applied)
    float* __restrict__ hst, const _Float16* __restrict__ Whh,
    const float* __restrict__ bhh, int TC, int first) {
  __shared__ __align__(16) _Float16 hL[2][16 * 256];
  __shared__ __align__(16) _Float16 WL[768 * 64];  // K-slice [192,256) of Wchh, swizzled
  const int tid = threadIdx.x;
  const int l = tid & 63, w = tid >> 6;  // 8 waves
  const int lrow = l & 15, lk = l >> 4;
  const int rbase = blockIdx.x * 16;

  half8 wf[6][6];  // kk 0..5 resident; kk 6..7 from LDS
#pragma unroll
  for (int g = 0; g < 3; ++g)
#pragma unroll
    for (int c = 0; c < 2; ++c) {
      const int nt = g * 16 + 2 * w + c;
#pragma unroll
      for (int kk = 0; kk < 6; ++kk)
        wf[g * 2 + c][kk] =
            *(const half8*)(Whh + (size_t)(nt * 16 + lrow) * P_DIM + kk * 32 + lk * 8);
    }
  for (int q = tid; q < 768 * 8; q += 512) {
    int row = q >> 3, slot = q & 7;
    int scol = (slot ^ (row & 7)) << 3;
    *(half8*)((char*)WL + (size_t)q * 16) = *(const half8*)(Whh + (size_t)row * P_DIM + 192 + scol);
  }
  float bN[2];
#pragma unroll
  for (int c = 0; c < 2; ++c) bN[c] = bhh[2 * P_DIM + 32 * w + 16 * c + lrow];

  float h[2][4];
#pragma unroll
  for (int c = 0; c < 2; ++c)
#pragma unroll
    for (int r = 0; r < 4; ++r)
      h[c][r] = first ? 0.f : hst[(rbase + lk * 4 + r) * P_DIM + 32 * w + 16 * c + lrow];
  for (int i = tid; i < 16 * 256; i += 512) {
    int row = i >> 8, pp = i & 255;
    float hv = first ? 0.f : hst[(rbase + row) * P_DIM + pp];
    int byte = (row * 512 + pp * 2) ^ ((row & 7) << 4);
    *(_Float16*)((char*)hL[0] + byte) = (_Float16)hv;
  }
  __syncthreads();

  half4 xA[3][2], xB[3][2];
  auto loadx = [&](half4(&X)[3][2], int tt) {
#pragma unroll
    for (int g = 0; g < 3; ++g)
#pragma unroll
      for (int c = 0; c < 2; ++c)
        X[g][c] = *(const half4*)(xpT + ((long)tt * 768 + g * 256 + 32 * w + 16 * c + lrow) * 256 +
                                  rbase + lk * 4);
  };
  auto step = [&](int tt, half4(&XC)[3][2], half4(&XN)[3][2], int tn) {
    loadx(XN, tn);
    char* hCur = (char*)hL[tt & 1];
    char* hNxt = (char*)hL[(tt & 1) ^ 1];
    half8 af[4];
    f32x4 acc[3][2];
#pragma unroll
    for (int c = 0; c < 2; ++c)
#pragma unroll
      for (int r = 0; r < 4; ++r) {
        acc[0][c][r] = (float)XC[0][c][r];
        acc[1][c][r] = (float)XC[1][c][r];
        acc[2][c][r] = 0.f;
      }
#pragma unroll
    for (int kk = 0; kk < 4; ++kk) {
      int byte = (lrow * 512 + (kk * 32 + lk * 8) * 2) ^ ((lrow & 7) << 4);
      af[kk] = *(const half8*)(hCur + byte);
    }
#pragma unroll
    for (int g = 0; g < 3; ++g)
#pragma unroll
      for (int c = 0; c < 2; ++c)
#pragma unroll
        for (int kk = 0; kk < 4; ++kk)
          acc[g][c] =
              __builtin_amdgcn_mfma_f32_16x16x32_f16(af[kk], wf[g * 2 + c][kk], acc[g][c], 0, 0, 0);
#pragma unroll
    for (int kk = 0; kk < 4; ++kk) {
      int byte = (lrow * 512 + ((kk + 4) * 32 + lk * 8) * 2) ^ ((lrow & 7) << 4);
      af[kk] = *(const half8*)(hCur + byte);
    }
#pragma unroll
    for (int g = 0; g < 3; ++g)
#pragma unroll
      for (int c = 0; c < 2; ++c) {
        const int nt = g * 16 + 2 * w + c;
        const int wrow = nt * 16 + lrow;
        f32x4 a = acc[g][c];
        a = __builtin_amdgcn_mfma_f32_16x16x32_f16(af[0], wf[g * 2 + c][4], a, 0, 0, 0);
        a = __builtin_amdgcn_mfma_f32_16x16x32_f16(af[1], wf[g * 2 + c][5], a, 0, 0, 0);
        half8 w6 = *(const half8*)((char*)WL + ((wrow * 128 + lk * 16) ^ ((wrow & 7) << 4)));
        half8 w7 = *(const half8*)((char*)WL + ((wrow * 128 + 64 + lk * 16) ^ ((wrow & 7) << 4)));
        a = __builtin_amdgcn_mfma_f32_16x16x32_f16(af[2], w6, a, 0, 0, 0);
        a = __builtin_amdgcn_mfma_f32_16x16x32_f16(af[3], w7, a, 0, 0, 0);
        acc[g][c] = a;
      }
#pragma unroll
    for (int c = 0; c < 2; ++c) {
      half4 hv4;
#pragma unroll
      for (int r = 0; r < 4; ++r) {
        float rg = sigm(acc[0][c][r]);
        float zg = sigm(acc[1][c][r]);
        float ng = tanh_f((float)XC[2][c][r] + rg * (acc[2][c][r] + bN[c]));
        float hv = (1.f - zg) * ng + zg * h[c][r];
        h[c][r] = hv;
        hv4[r] = (_Float16)hv;
        const int row = lk * 4 + r, pp = 32 * w + 16 * c + lrow;
        int byte = (row * 512 + pp * 2) ^ ((row & 7) << 4);
        *(_Float16*)(hNxt + byte) = hv4[r];
      }
      *(half4*)(hT + ((long)tt * 256 + 32 * w + 16 * c + lrow) * 256 + rbase + lk * 4) = hv4;
    }
    __syncthreads();
  };
  loadx(xA, 0);
  for (int t = 0; t < TC; t += 2) {
    step(t, xA, xB, t + 1);
    step(t + 1, xB, xA, (t + 2 < TC) ? t + 2 : TC - 1);
  }
#pragma unroll
  for (int c = 0; c < 2; ++c)
#pragma unroll
    for (int r = 0; r < 4; ++r)
      hst[(rbase + lk * 4 + r) * P_DIM + 32 * w + 16 * c + lrow] = h[c][r];
}

// ---------------- gelu + mean over t: aggT[p][b] = sum_t gelu(hT[t][p][b]) --------
__global__ void gelu_mean_k(const _Float16* __restrict__ hT, float* __restrict__ aggT) {
  int p = blockIdx.x, b = threadIdx.x;  // 256 blocks x 256 threads
  float s = 0.f;
  for (int t = 0; t < T_DIM; ++t) {
    float v = (float)hT[((long)t * P_DIM + p) * B_DIM + b];
    s += 0.5f * v * (1.f + erff(v * 0.70710678118f));
  }
  aggT[p * B_DIM + b] = s;
}

// ---------------- final: out = (aggT/T + skipm) @ Wf^T + bf ----------------
__global__ void final_k(const float* __restrict__ aggT, const float* __restrict__ skipm,
                        const float* __restrict__ Wf, const float* __restrict__ bfb,
                        float* __restrict__ out) {
  int b = blockIdx.x, o = threadIdx.x;  // 64 threads
  if (o >= O_DIM) return;
  float s = bfb[o];
  for (int p = 0; p < P_DIM; ++p)
    s += (aggT[p * B_DIM + b] * (1.0f / T_DIM) + skipm[b * P_DIM + p]) * Wf[o * P_DIM + p];
  out[b * O_DIM + o] = s;
}

extern "C" void kernel_launch(void* const* d_in, const int* in_sizes, int n_in, void* d_out,
                              int out_size, void* d_ws, size_t ws_size, hipStream_t stream) {
  const float* x = (const float*)d_in[0];
  const float* h0 = (const float*)d_in[1];
  const float* Wih0 = (const float*)d_in[2];
  const float* Whh0f = (const float*)d_in[3];
  const float* bih0 = (const float*)d_in[4];
  const float* bhh0 = (const float*)d_in[5];
  const float* Wih1 = (const float*)d_in[6];
  const float* Whh1f = (const float*)d_in[7];
  const float* bih1 = (const float*)d_in[8];
  const float* bhh1 = (const float*)d_in[9];
  const float* Wp = (const float*)d_in[10];
  const float* bp = (const float*)d_in[11];
  const float* gamma = (const float*)d_in[12];
  const float* beta = (const float*)d_in[13];
  const float* Wcih = (const float*)d_in[14];
  const float* Wchhf = (const float*)d_in[15];
  const float* bcih = (const float*)d_in[16];
  const float* bchh = (const float*)d_in[17];
  const float* Wsk = (const float*)d_in[18];
  const float* bsk = (const float*)d_in[19];
  const float* Wf = (const float*)d_in[20];
  const float* bfb = (const float*)d_in[21];
  float* out = (float*)d_out;

  char* wsp = (char*)d_ws;
  size_t off = 0;
  auto alloc = [&](size_t b) -> void* {
    void* p = wsp + off;
    off = (off + b + 255) & ~(size_t)255;
    return p;
  };
  _Float16* xh = (_Float16*)alloc((size_t)T_DIM * B_DIM * I_DIM * 2);
  _Float16* wih0 = (_Float16*)alloc(384 * 64 * 2);
  _Float16* whh0 = (_Float16*)alloc(384 * 128 * 2);
  _Float16* wih1 = (_Float16*)alloc(384 * 128 * 2);
  _Float16* whh1 = (_Float16*)alloc(384 * 128 * 2);
  _Float16* wp = (_Float16*)alloc(256 * 128 * 2);
  _Float16* wcihF = (_Float16*)alloc(768 * 256 * 2);
  _Float16* wchh = (_Float16*)alloc(768 * 256 * 2);
  _Float16* y01 = (_Float16*)alloc((size_t)T_DIM * B_DIM * H_DIM * 2);
  _Float16* proj = (_Float16*)alloc((size_t)T_DIM * B_DIM * P_DIM * 2);
  _Float16* hT = (_Float16*)alloc((size_t)T_DIM * B_DIM * P_DIM * 2);
  float* hst0 = (float*)alloc(B_DIM * H_DIM * 4);
  float* hst1 = (float*)alloc(B_DIM * H_DIM * 4);
  float* hstc = (float*)alloc(B_DIM * P_DIM * 4);
  float* aggT = (float*)alloc(B_DIM * P_DIM * 4);
  float* xm = (float*)alloc(B_DIM * I_DIM * 4);
  float* skipm = (float*)alloc(B_DIM * P_DIM * 4);
  float* gsum = (float*)alloc(256 * 4);
  float* gss = (float*)alloc(256 * 4);
  float* bns = (float*)alloc(256 * 4);
  float* bnt = (float*)alloc(256 * 4);
  float* bcihF = (float*)alloc(768 * 4);

  int TC = 512;  // time-chunk; shrink until xp chunk buffer fits in ws
  while (TC > 8 && off + (size_t)TC * B_DIM * 768 * 2 > ws_size) TC >>= 1;
  _Float16* xpb = (_Float16*)alloc((size_t)TC * B_DIM * 768 * 2);
  const int nc = T_DIM / TC;
  const int M = TC * B_DIM;

  auto cvt = [&](const float* s, _Float16* d, long n) {
    long g = (n + 255) / 256;
    if (g > 2048) g = 2048;
    cvt_k<<<dim3((unsigned)g), dim3(256), 0, stream>>>(s, d, n);
  };
  cvt(x, xh, (long)T_DIM * B_DIM * I_DIM);
  cvt(Wih0, wih0, 384 * 64);
  cvt(Whh0f, whh0, 384 * 128);
  cvt(Wih1, wih1, 384 * 128);
  cvt(Whh1f, whh1, 384 * 128);
  cvt(Wp, wp, 256 * 128);
  cvt(Wchhf, wchh, 768 * 256);

  xmean_k<<<B_DIM, I_DIM, 0, stream>>>(x, xm);
  skip_k<<<B_DIM, P_DIM, 0, stream>>>(xm, Wsk, bsk, skipm);
  zero2_k<<<1, 256, 0, stream>>>(gsum, gss);

  for (int c = 0; c < nc; ++c) {
    const _Float16* xc = xh + (size_t)c * TC * B_DIM * I_DIM;
    _Float16* yc = y01 + (size_t)c * TC * B_DIM * H_DIM;
    _Float16* pc = proj + (size_t)c * TC * B_DIM * P_DIM;
    gemm_k<<<dim3(M / 128, 3), 256, 0, stream>>>(xc, wih0, bih0, bhh0, 2 * H_DIM, xpb, M,
                                                 3 * H_DIM, I_DIM, 1);
    scan_layer<<<16, 512, 0, stream>>>(xpb, yc, hst0, h0, whh0, bhh0, TC, c == 0);
    gemm_k<<<dim3(M / 128, 3), 256, 0, stream>>>(yc, wih1, bih1, bhh1, 2 * H_DIM, xpb, M,
                                                 3 * H_DIM, H_DIM, 1);
    scan_layer<<<16, 512, 0, stream>>>(xpb, yc, hst1, h0 + B_DIM * H_DIM, whh1, bhh1, TC, c == 0);
    gemm_k<<<dim3(M / 128, 2), 256, 0, stream>>>(yc, wp, bp, (const float*)nullptr, 0, pc, M,
                                                 P_DIM, H_DIM, 0);
  }
  stats_k<<<512, 256, 0, stream>>>(proj, gsum, gss);
  bnprep_k<<<1, 256, 0, stream>>>(gsum, gss, gamma, beta, bns, bnt);
  fold_k<<<768, 256, 0, stream>>>(Wcih, bcih, bns, bnt, wcihF, bcihF);
  for (int c = 0; c < nc; ++c) {
    const _Float16* pc = proj + (size_t)c * TC * B_DIM * P_DIM;
    gemm_k<<<dim3(M / 128, 6), 256, 0, stream>>>(pc, wcihF, bcihF, bchh, 2 * P_DIM, xpb, M,
                                                 3 * P_DIM, P_DIM, 1);
    scan_cell<<<16, 512, 0, stream>>>(xpb, hT + (size_t)c * TC * B_DIM * P_DIM, hstc, wchh, bchh,
                                      TC, c == 0);
  }
  gelu_mean_k<<<P_DIM, B_DIM, 0, stream>>>(hT, aggT);
  final_k<<<B_DIM, 64, 0, stream>>>(aggT, skipm, Wf, bfb, out);
}

// Round 3
// 2945.460 us; speedup vs baseline: 1.4374x; 1.2284x over previous
//
#include <hip/hip_runtime.h>

#define T_DIM 512
#define B_DIM 256
#define I_DIM 64
#define H_DIM 128
#define P_DIM 256
#define O_DIM 50

typedef _Float16 half8 __attribute__((ext_vector_type(8)));
typedef _Float16 half4 __attribute__((ext_vector_type(4)));
typedef float f32x4 __attribute__((ext_vector_type(4)));

#define GLOAD_LDS16(G, L)                                                      \
  __builtin_amdgcn_global_load_lds(                                            \
      (const __attribute__((address_space(1))) void*)(G),                      \
      (__attribute__((address_space(3))) void*)(L), 16, 0, 0)

// fast sigmoid/tanh: v_rcp_f32 instead of IEEE divide (saves ~10 instr each)
__device__ __forceinline__ float sigm(float x) {
  return __builtin_amdgcn_rcpf(1.f + __expf(-x));
}
__device__ __forceinline__ float tanh_f(float x) {
  x = fminf(20.f, fmaxf(-20.f, x));
  float e = __expf(2.f * x);
  return (e - 1.f) * __builtin_amdgcn_rcpf(e + 1.f);
}

// ---------------- elementwise fp32 -> fp16 ----------------
__global__ void cvt_k(const float* __restrict__ s, _Float16* __restrict__ d, long n) {
  long i = (long)blockIdx.x * blockDim.x + threadIdx.x;
  long st = (long)gridDim.x * blockDim.x;
  for (; i < n; i += st) d[i] = (_Float16)s[i];
}

// ---------------- mean over t of x -> xmean [B,I] ----------------
__global__ void xmean_k(const float* __restrict__ x, float* __restrict__ xm) {
  int b = blockIdx.x, i = threadIdx.x;  // 64 threads
  float s = 0.f;
  for (int t = 0; t < T_DIM; ++t) s += x[((long)t * B_DIM + b) * I_DIM + i];
  xm[b * I_DIM + i] = s * (1.0f / T_DIM);
}

// ---------------- skip_mean = xmean @ Ws^T + bs ----------------
__global__ void skip_k(const float* __restrict__ xm, const float* __restrict__ Wsk,
                       const float* __restrict__ bsk, float* __restrict__ skipm) {
  int b = blockIdx.x, p = threadIdx.x;  // 256 threads
  float s = bsk[p];
  for (int i = 0; i < I_DIM; ++i) s += xm[b * I_DIM + i] * Wsk[p * I_DIM + i];
  skipm[b * P_DIM + p] = s;
}

__global__ void zero2_k(float* a, float* b2) {
  int p = threadIdx.x;
  a[p] = 0.f;
  b2[p] = 0.f;
}

// ---------------- BN stats over proj (fp16, row-major) ----------------
__global__ void stats_k(const _Float16* __restrict__ proj, float* __restrict__ gsum,
                        float* __restrict__ gss) {
  int p = threadIdx.x;
  long r0 = (long)blockIdx.x * 256;
  float s = 0.f, ss = 0.f;
  for (int r = 0; r < 256; ++r) {
    float v = (float)proj[(r0 + r) * P_DIM + p];
    s += v;
    ss += v * v;
  }
  atomicAdd(&gsum[p], s);
  atomicAdd(&gss[p], ss);
}

__global__ void bnprep_k(const float* gsum, const float* gss, const float* gamma,
                         const float* beta, float* bns, float* bnt) {
  int p = threadIdx.x;
  const float inv = 1.0f / ((float)T_DIM * (float)B_DIM);
  float m = gsum[p] * inv;
  float v = gss[p] * inv - m * m;
  float rs = rsqrtf(v + 1e-5f);
  float s = gamma[p] * rs;
  bns[p] = s;
  bnt[p] = beta[p] - m * s;
}

// fold BN affine into Wcih (per-column scale) + bias
__global__ void fold_k(const float* __restrict__ Wcih, const float* __restrict__ bcih,
                       const float* __restrict__ bns, const float* __restrict__ bnt,
                       _Float16* __restrict__ WF, float* __restrict__ bF) {
  __shared__ float red[256];
  int n = blockIdx.x, k = threadIdx.x;
  float wv = Wcih[n * 256 + k];
  WF[n * 256 + k] = (_Float16)(wv * bns[k]);
  red[k] = wv * bnt[k];
  __syncthreads();
  for (int s = 128; s > 0; s >>= 1) {
    if (k < s) red[k] += red[k + s];
    __syncthreads();
  }
  if (k == 0) bF[n] = bcih[n] + red[0];
}

// ---------------- fp16 MFMA GEMM: C = A[M,K] @ W[N,K]^T + bias (+bias2 n<n2lim)
// transN=0: C row-major [M][N].  transN=1: C = [t][N][B] with M = t*256+b.
__global__ __launch_bounds__(256) void gemm_k(
    const _Float16* __restrict__ A, const _Float16* __restrict__ W,
    const float* __restrict__ bias, const float* __restrict__ bias2, int n2lim,
    _Float16* __restrict__ C, int M, int N, int K, int transN) {
  __shared__ __align__(16) _Float16 As[128 * 64];
  __shared__ __align__(16) _Float16 Bs[128 * 64];
  const int tid = threadIdx.x;
  const int l = tid & 63;
  const int w = tid >> 6;
  const int wr = w >> 1, wc = w & 1;
  const int lrow = l & 15, lk = l >> 4;
  const long bm = blockIdx.x, bn = blockIdx.y;

  f32x4 z = {0.f, 0.f, 0.f, 0.f};
  f32x4 acc[4][4];
#pragma unroll
  for (int m = 0; m < 4; ++m)
#pragma unroll
    for (int n = 0; n < 4; ++n) acc[m][n] = z;

  for (int k0 = 0; k0 < K; k0 += 64) {
    if (k0) __syncthreads();
#pragma unroll
    for (int it = 0; it < 4; ++it) {
      const int lin = it * 256 + tid;
      const int row = lin >> 3, slot = lin & 7;
      const int scol = (slot ^ (row & 7)) << 3;  // pre-swizzled global source
      GLOAD_LDS16(A + (bm * 128 + row) * (long)K + k0 + scol, (_Float16*)As + (size_t)lin * 8);
      GLOAD_LDS16(W + (bn * 128 + row) * (long)K + k0 + scol, (_Float16*)Bs + (size_t)lin * 8);
    }
    __syncthreads();
#pragma unroll
    for (int kk = 0; kk < 2; ++kk) {
      half8 af[4], wfr[4];
#pragma unroll
      for (int m = 0; m < 4; ++m) {
        const int row = wr * 64 + m * 16 + lrow;
        af[m] = *(const half8*)((const char*)As +
                                ((row * 128 + (kk * 32 + lk * 8) * 2) ^ ((row & 7) << 4)));
      }
#pragma unroll
      for (int n = 0; n < 4; ++n) {
        const int row = wc * 64 + n * 16 + lrow;
        wfr[n] = *(const half8*)((const char*)Bs +
                                 ((row * 128 + (kk * 32 + lk * 8) * 2) ^ ((row & 7) << 4)));
      }
#pragma unroll
      for (int m = 0; m < 4; ++m)
#pragma unroll
        for (int n = 0; n < 4; ++n)
          acc[m][n] = __builtin_amdgcn_mfma_f32_16x16x32_f16(af[m], wfr[n], acc[m][n], 0, 0, 0);
    }
  }
  if (transN) {
    const long tIdx = bm >> 1;  // B=256, 128-row tiles
    const int bbase = (int)(bm & 1) * 128 + wr * 64 + lk * 4;
#pragma unroll
    for (int n = 0; n < 4; ++n) {
      const int gn = (int)bn * 128 + wc * 64 + n * 16 + lrow;
      float bv = 0.f;
      if (bias) bv += bias[gn];
      if (bias2 && gn < n2lim) bv += bias2[gn];
#pragma unroll
      for (int m = 0; m < 4; ++m) {
        half4 v;
#pragma unroll
        for (int r = 0; r < 4; ++r) v[r] = (_Float16)(acc[m][n][r] + bv);
        *(half4*)(C + (tIdx * N + gn) * 256 + bbase + m * 16) = v;
      }
    }
  } else {
#pragma unroll
    for (int n = 0; n < 4; ++n) {
      const int gn = (int)bn * 128 + wc * 64 + n * 16 + lrow;
      float bv = 0.f;
      if (bias) bv += bias[gn];
      if (bias2 && gn < n2lim) bv += bias2[gn];
#pragma unroll
      for (int m = 0; m < 4; ++m)
#pragma unroll
        for (int r = 0; r < 4; ++r) {
          const long gm = bm * 128 + wr * 64 + m * 16 + lk * 4 + r;
          C[gm * (long)N + gn] = (_Float16)(acc[m][n][r] + bv);
        }
    }
  }
}

// ---------------- GRU layer scan: 16 blocks x 8 waves, 4 h/thread ----------------
__global__ __launch_bounds__(512, 2) void scan_layer(
    const _Float16* __restrict__ xpT,  // [TC][384][B] incl. bih + bhh(r,z)
    _Float16* __restrict__ y,          // [TC*B][128] row-major
    float* __restrict__ hst, const float* __restrict__ h0init,
    const _Float16* __restrict__ Whh, const float* __restrict__ bhh, int TC, int first) {
  __shared__ __align__(16) _Float16 hL[2][16 * 128];
  const int tid = threadIdx.x;
  const int l = tid & 63, w = tid >> 6;  // 8 waves
  const int lrow = l & 15, lk = l >> 4;
  const int rbase = blockIdx.x * 16;
  const int p = w * 16 + lrow;

  half8 wf[3][4];  // wave owns p-tile w for all 3 gates
#pragma unroll
  for (int g = 0; g < 3; ++g)
#pragma unroll
    for (int kk = 0; kk < 4; ++kk)
      wf[g][kk] = *(const half8*)(Whh + (size_t)(g * 128 + p) * H_DIM + kk * 32 + lk * 8);
  const float bN = bhh[2 * H_DIM + p];

  const float* hsrc = first ? h0init : hst;
  float h[4];
#pragma unroll
  for (int r = 0; r < 4; ++r) h[r] = hsrc[(rbase + lk * 4 + r) * H_DIM + p];
  for (int i = tid; i < 16 * 128; i += 512) {
    int row = i >> 7, pp = i & 127;
    int byte = (row * 256 + pp * 2) ^ ((row & 7) << 4);
    *(_Float16*)((char*)hL[0] + byte) = (_Float16)hsrc[(rbase + row) * H_DIM + pp];
  }
  __syncthreads();

  half4 xA[3], xB[3];
  auto loadx = [&](half4(&X)[3], int tt) {
#pragma unroll
    for (int g = 0; g < 3; ++g)
      X[g] = *(const half4*)(xpT + ((long)tt * 384 + g * 128 + p) * 256 + rbase + lk * 4);
  };
  auto step = [&](int tt, half4(&XC)[3], half4(&XN)[3], int tn) {
    loadx(XN, tn);  // prefetch next step's xp
    char* hCur = (char*)hL[tt & 1];
    char* hNxt = (char*)hL[(tt & 1) ^ 1];
    half8 af[4];
#pragma unroll
    for (int kk = 0; kk < 4; ++kk) {
      int byte = (lrow * 256 + (kk * 32 + lk * 8) * 2) ^ ((lrow & 7) << 4);
      af[kk] = *(const half8*)(hCur + byte);
    }
    f32x4 acc[3];
#pragma unroll
    for (int r = 0; r < 4; ++r) {
      acc[0][r] = (float)XC[0][r];
      acc[1][r] = (float)XC[1][r];
      acc[2][r] = 0.f;
    }
#pragma unroll
    for (int g = 0; g < 3; ++g)
#pragma unroll
      for (int kk = 0; kk < 4; ++kk)
        acc[g] = __builtin_amdgcn_mfma_f32_16x16x32_f16(af[kk], wf[g][kk], acc[g], 0, 0, 0);
#pragma unroll
    for (int r = 0; r < 4; ++r) {
      float rg = sigm(acc[0][r]);
      float zg = sigm(acc[1][r]);
      float ng = tanh_f((float)XC[2][r] + rg * (acc[2][r] + bN));
      float hv = ng + zg * (h[r] - ng);
      h[r] = hv;
      const int row = lk * 4 + r;
      y[((long)tt * B_DIM + rbase + row) * H_DIM + p] = (_Float16)hv;
      int byte = (row * 256 + p * 2) ^ ((row & 7) << 4);
      *(_Float16*)(hNxt + byte) = (_Float16)hv;
    }
    __syncthreads();
  };
  loadx(xA, 0);
  for (int t = 0; t < TC; t += 2) {
    step(t, xA, xB, t + 1);
    step(t + 1, xB, xA, (t + 2 < TC) ? t + 2 : TC - 1);
  }
#pragma unroll
  for (int r = 0; r < 4; ++r) hst[(rbase + lk * 4 + r) * H_DIM + p] = h[r];
}

// ---------------- GRUCell scan (P=256): 16 blocks x 8 waves ----------------
__global__ __launch_bounds__(512, 2) void scan_cell(
    const _Float16* __restrict__ xpT,  // [TC][768][B] incl. folded biases
    _Float16* __restrict__ hT,         // [TC][256][B] (chunk-offset applied)
    float* __restrict__ hst, const _Float16* __restrict__ Whh,
    const float* __restrict__ bhh, int TC, int first) {
  __shared__ __align__(16) _Float16 hL[2][16 * 256];
  __shared__ __align__(16) _Float16 WL[768 * 64];  // K-slice [192,256) of Wchh, swizzled
  const int tid = threadIdx.x;
  const int l = tid & 63, w = tid >> 6;  // 8 waves
  const int lrow = l & 15, lk = l >> 4;
  const int rbase = blockIdx.x * 16;

  half8 wf[6][6];  // kk 0..5 resident; kk 6..7 from LDS
#pragma unroll
  for (int g = 0; g < 3; ++g)
#pragma unroll
    for (int c = 0; c < 2; ++c) {
      const int nt = g * 16 + 2 * w + c;
#pragma unroll
      for (int kk = 0; kk < 6; ++kk)
        wf[g * 2 + c][kk] =
            *(const half8*)(Whh + (size_t)(nt * 16 + lrow) * P_DIM + kk * 32 + lk * 8);
    }
  for (int q = tid; q < 768 * 8; q += 512) {
    int row = q >> 3, slot = q & 7;
    int scol = (slot ^ (row & 7)) << 3;
    *(half8*)((char*)WL + (size_t)q * 16) = *(const half8*)(Whh + (size_t)row * P_DIM + 192 + scol);
  }
  float bN[2];
#pragma unroll
  for (int c = 0; c < 2; ++c) bN[c] = bhh[2 * P_DIM + 32 * w + 16 * c + lrow];

  float h[2][4];
#pragma unroll
  for (int c = 0; c < 2; ++c)
#pragma unroll
    for (int r = 0; r < 4; ++r)
      h[c][r] = first ? 0.f : hst[(rbase + lk * 4 + r) * P_DIM + 32 * w + 16 * c + lrow];
  for (int i = tid; i < 16 * 256; i += 512) {
    int row = i >> 8, pp = i & 255;
    float hv = first ? 0.f : hst[(rbase + row) * P_DIM + pp];
    int byte = (row * 512 + pp * 2) ^ ((row & 7) << 4);
    *(_Float16*)((char*)hL[0] + byte) = (_Float16)hv;
  }
  __syncthreads();

  half4 xA[3][2], xB[3][2];
  auto loadx = [&](half4(&X)[3][2], int tt) {
#pragma unroll
    for (int g = 0; g < 3; ++g)
#pragma unroll
      for (int c = 0; c < 2; ++c)
        X[g][c] = *(const half4*)(xpT + ((long)tt * 768 + g * 256 + 32 * w + 16 * c + lrow) * 256 +
                                  rbase + lk * 4);
  };
  auto step = [&](int tt, half4(&XC)[3][2], half4(&XN)[3][2], int tn) {
    loadx(XN, tn);
    char* hCur = (char*)hL[tt & 1];
    char* hNxt = (char*)hL[(tt & 1) ^ 1];
    half8 af[4];
    f32x4 acc[3][2];
#pragma unroll
    for (int c = 0; c < 2; ++c)
#pragma unroll
      for (int r = 0; r < 4; ++r) {
        acc[0][c][r] = (float)XC[0][c][r];
        acc[1][c][r] = (float)XC[1][c][r];
        acc[2][c][r] = 0.f;
      }
#pragma unroll
    for (int kk = 0; kk < 4; ++kk) {
      int byte = (lrow * 512 + (kk * 32 + lk * 8) * 2) ^ ((lrow & 7) << 4);
      af[kk] = *(const half8*)(hCur + byte);
    }
#pragma unroll
    for (int g = 0; g < 3; ++g)
#pragma unroll
      for (int c = 0; c < 2; ++c)
#pragma unroll
        for (int kk = 0; kk < 4; ++kk)
          acc[g][c] =
              __builtin_amdgcn_mfma_f32_16x16x32_f16(af[kk], wf[g * 2 + c][kk], acc[g][c], 0, 0, 0);
#pragma unroll
    for (int kk = 0; kk < 4; ++kk) {
      int byte = (lrow * 512 + ((kk + 4) * 32 + lk * 8) * 2) ^ ((lrow & 7) << 4);
      af[kk] = *(const half8*)(hCur + byte);
    }
#pragma unroll
    for (int g = 0; g < 3; ++g)
#pragma unroll
      for (int c = 0; c < 2; ++c) {
        const int nt = g * 16 + 2 * w + c;
        const int wrow = nt * 16 + lrow;
        f32x4 a = acc[g][c];
        a = __builtin_amdgcn_mfma_f32_16x16x32_f16(af[0], wf[g * 2 + c][4], a, 0, 0, 0);
        a = __builtin_amdgcn_mfma_f32_16x16x32_f16(af[1], wf[g * 2 + c][5], a, 0, 0, 0);
        half8 w6 = *(const half8*)((char*)WL + ((wrow * 128 + lk * 16) ^ ((wrow & 7) << 4)));
        half8 w7 = *(const half8*)((char*)WL + ((wrow * 128 + 64 + lk * 16) ^ ((wrow & 7) << 4)));
        a = __builtin_amdgcn_mfma_f32_16x16x32_f16(af[2], w6, a, 0, 0, 0);
        a = __builtin_amdgcn_mfma_f32_16x16x32_f16(af[3], w7, a, 0, 0, 0);
        acc[g][c] = a;
      }
#pragma unroll
    for (int c = 0; c < 2; ++c) {
      half4 hv4;
#pragma unroll
      for (int r = 0; r < 4; ++r) {
        float rg = sigm(acc[0][c][r]);
        float zg = sigm(acc[1][c][r]);
        float ng = tanh_f((float)XC[2][c][r] + rg * (acc[2][c][r] + bN[c]));
        float hv = ng + zg * (h[c][r] - ng);
        h[c][r] = hv;
        hv4[r] = (_Float16)hv;
        const int row = lk * 4 + r, pp = 32 * w + 16 * c + lrow;
        int byte = (row * 512 + pp * 2) ^ ((row & 7) << 4);
        *(_Float16*)(hNxt + byte) = hv4[r];
      }
      *(half4*)(hT + ((long)tt * 256 + 32 * w + 16 * c + lrow) * 256 + rbase + lk * 4) = hv4;
    }
    __syncthreads();
  };
  loadx(xA, 0);
  for (int t = 0; t < TC; t += 2) {
    step(t, xA, xB, t + 1);
    step(t + 1, xB, xA, (t + 2 < TC) ? t + 2 : TC - 1);
  }
#pragma unroll
  for (int c = 0; c < 2; ++c)
#pragma unroll
    for (int r = 0; r < 4; ++r)
      hst[(rbase + lk * 4 + r) * P_DIM + 32 * w + 16 * c + lrow] = h[c][r];
}

// ---------------- gelu + mean over t: aggT[p][b] = sum_t gelu(hT[t][p][b]) --------
__global__ void gelu_mean_k(const _Float16* __restrict__ hT, float* __restrict__ aggT) {
  int p = blockIdx.x, b = threadIdx.x;  // 256 blocks x 256 threads
  float s = 0.f;
  for (int t = 0; t < T_DIM; ++t) {
    float v = (float)hT[((long)t * P_DIM + p) * B_DIM + b];
    s += 0.5f * v * (1.f + erff(v * 0.70710678118f));
  }
  aggT[p * B_DIM + b] = s;
}

// ---------------- final: out = (aggT/T + skipm) @ Wf^T + bf ----------------
__global__ void final_k(const float* __restrict__ aggT, const float* __restrict__ skipm,
                        const float* __restrict__ Wf, const float* __restrict__ bfb,
                        float* __restrict__ out) {
  int b = blockIdx.x, o = threadIdx.x;  // 64 threads
  if (o >= O_DIM) return;
  float s = bfb[o];
  for (int p = 0; p < P_DIM; ++p)
    s += (aggT[p * B_DIM + b] * (1.0f / T_DIM) + skipm[b * P_DIM + p]) * Wf[o * P_DIM + p];
  out[b * O_DIM + o] = s;
}

extern "C" void kernel_launch(void* const* d_in, const int* in_sizes, int n_in, void* d_out,
                              int out_size, void* d_ws, size_t ws_size, hipStream_t stream) {
  const float* x = (const float*)d_in[0];
  const float* h0 = (const float*)d_in[1];
  const float* Wih0 = (const float*)d_in[2];
  const float* Whh0f = (const float*)d_in[3];
  const float* bih0 = (const float*)d_in[4];
  const float* bhh0 = (const float*)d_in[5];
  const float* Wih1 = (const float*)d_in[6];
  const float* Whh1f = (const float*)d_in[7];
  const float* bih1 = (const float*)d_in[8];
  const float* bhh1 = (const float*)d_in[9];
  const float* Wp = (const float*)d_in[10];
  const float* bp = (const float*)d_in[11];
  const float* gamma = (const float*)d_in[12];
  const float* beta = (const float*)d_in[13];
  const float* Wcih = (const float*)d_in[14];
  const float* Wchhf = (const float*)d_in[15];
  const float* bcih = (const float*)d_in[16];
  const float* bchh = (const float*)d_in[17];
  const float* Wsk = (const float*)d_in[18];
  const float* bsk = (const float*)d_in[19];
  const float* Wf = (const float*)d_in[20];
  const float* bfb = (const float*)d_in[21];
  float* out = (float*)d_out;

  char* wsp = (char*)d_ws;
  size_t off = 0;
  auto alloc = [&](size_t b) -> void* {
    void* p = wsp + off;
    off = (off + b + 255) & ~(size_t)255;
    return p;
  };
  _Float16* xh = (_Float16*)alloc((size_t)T_DIM * B_DIM * I_DIM * 2);
  _Float16* wih0 = (_Float16*)alloc(384 * 64 * 2);
  _Float16* whh0 = (_Float16*)alloc(384 * 128 * 2);
  _Float16* wih1 = (_Float16*)alloc(384 * 128 * 2);
  _Float16* whh1 = (_Float16*)alloc(384 * 128 * 2);
  _Float16* wp = (_Float16*)alloc(256 * 128 * 2);
  _Float16* wcihF = (_Float16*)alloc(768 * 256 * 2);
  _Float16* wchh = (_Float16*)alloc(768 * 256 * 2);
  _Float16* y01 = (_Float16*)alloc((size_t)T_DIM * B_DIM * H_DIM * 2);
  _Float16* proj = (_Float16*)alloc((size_t)T_DIM * B_DIM * P_DIM * 2);
  _Float16* hT = (_Float16*)alloc((size_t)T_DIM * B_DIM * P_DIM * 2);
  float* hst0 = (float*)alloc(B_DIM * H_DIM * 4);
  float* hst1 = (float*)alloc(B_DIM * H_DIM * 4);
  float* hstc = (float*)alloc(B_DIM * P_DIM * 4);
  float* aggT = (float*)alloc(B_DIM * P_DIM * 4);
  float* xm = (float*)alloc(B_DIM * I_DIM * 4);
  float* skipm = (float*)alloc(B_DIM * P_DIM * 4);
  float* gsum = (float*)alloc(256 * 4);
  float* gss = (float*)alloc(256 * 4);
  float* bns = (float*)alloc(256 * 4);
  float* bnt = (float*)alloc(256 * 4);
  float* bcihF = (float*)alloc(768 * 4);

  int TC = 512;  // time-chunk; shrink until xp chunk buffer fits in ws
  while (TC > 8 && off + (size_t)TC * B_DIM * 768 * 2 > ws_size) TC >>= 1;
  _Float16* xpb = (_Float16*)alloc((size_t)TC * B_DIM * 768 * 2);
  const int nc = T_DIM / TC;
  const int M = TC * B_DIM;

  auto cvt = [&](const float* s, _Float16* d, long n) {
    long g = (n + 255) / 256;
    if (g > 2048) g = 2048;
    cvt_k<<<dim3((unsigned)g), dim3(256), 0, stream>>>(s, d, n);
  };
  cvt(x, xh, (long)T_DIM * B_DIM * I_DIM);
  cvt(Wih0, wih0, 384 * 64);
  cvt(Whh0f, whh0, 384 * 128);
  cvt(Wih1, wih1, 384 * 128);
  cvt(Whh1f, whh1, 384 * 128);
  cvt(Wp, wp, 256 * 128);
  cvt(Wchhf, wchh, 768 * 256);

  xmean_k<<<B_DIM, I_DIM, 0, stream>>>(x, xm);
  skip_k<<<B_DIM, P_DIM, 0, stream>>>(xm, Wsk, bsk, skipm);
  zero2_k<<<1, 256, 0, stream>>>(gsum, gss);

  for (int c = 0; c < nc; ++c) {
    const _Float16* xc = xh + (size_t)c * TC * B_DIM * I_DIM;
    _Float16* yc = y01 + (size_t)c * TC * B_DIM * H_DIM;
    _Float16* pc = proj + (size_t)c * TC * B_DIM * P_DIM;
    gemm_k<<<dim3(M / 128, 3), 256, 0, stream>>>(xc, wih0, bih0, bhh0, 2 * H_DIM, xpb, M,
                                                 3 * H_DIM, I_DIM, 1);
    scan_layer<<<16, 512, 0, stream>>>(xpb, yc, hst0, h0, whh0, bhh0, TC, c == 0);
    gemm_k<<<dim3(M / 128, 3), 256, 0, stream>>>(yc, wih1, bih1, bhh1, 2 * H_DIM, xpb, M,
                                                 3 * H_DIM, H_DIM, 1);
    scan_layer<<<16, 512, 0, stream>>>(xpb, yc, hst1, h0 + B_DIM * H_DIM, whh1, bhh1, TC, c == 0);
    gemm_k<<<dim3(M / 128, 2), 256, 0, stream>>>(yc, wp, bp, (const float*)nullptr, 0, pc, M,
                                                 P_DIM, H_DIM, 0);
  }
  stats_k<<<512, 256, 0, stream>>>(proj, gsum, gss);
  bnprep_k<<<1, 256, 0, stream>>>(gsum, gss, gamma, beta, bns, bnt);
  fold_k<<<768, 256, 0, stream>>>(Wcih, bcih, bns, bnt, wcihF, bcihF);
  for (int c = 0; c < nc; ++c) {
    const _Float16* pc = proj + (size_t)c * TC * B_DIM * P_DIM;
    gemm_k<<<dim3(M / 128, 6), 256, 0, stream>>>(pc, wcihF, bcihF, bchh, 2 * P_DIM, xpb, M,
                                                 3 * P_DIM, P_DIM, 1);
    scan_cell<<<16, 512, 0, stream>>>(xpb, hT + (size_t)c * TC * B_DIM * P_DIM, hstc, wchh, bchh,
                                      TC, c == 0);
  }
  gelu_mean_k<<<P_DIM, B_DIM, 0, stream>>>(hT, aggT);
  final_k<<<B_DIM, 64, 0, stream>>>(aggT, skipm, Wf, bfb, out);
}